// Round 4
// baseline (85.904 us; speedup 1.0000x reference)
//
#include <hip/hip_runtime.h>
#include <math.h>

#define N 64
#define F 64
#define W 40
#define D 512
#define LSM 9.0f
#define LLSE 6.0f
#define MARG 0.2f

typedef _Float16 f16x8 __attribute__((ext_vector_type(8)));
typedef _Float16 f16x4 __attribute__((ext_vector_type(4)));
typedef float f32x4 __attribute__((ext_vector_type(4)));

__device__ inline void gll16(const void* g, void* l) {
  __builtin_amdgcn_global_load_lds(
      (const __attribute__((address_space(1))) unsigned int*)g,
      (__attribute__((address_space(3))) unsigned int*)l, 16, 0, 0);
}

// layouts (halves):
//  img_h per i: 64*512 linear [f][d]                                  (32768)
//  cap_h per j: [ch][w48][128], half-idx ^ ((w&7)<<3), rows 40..47=0  (24576)
//  G_h  per j: [w48][64], ^ ((w&7)<<3), zero outside 40x40            (3072)

// ---------------- k_pre ----------------
// blocks [0,64): img convert fp16 (single pass) + n1 row norms
// blocks [64,128): cap convert fp16 swizzled (global + LDS) + Gram via MFMA
__global__ __launch_bounds__(256) void k_pre(
    const float* __restrict__ img, const float* __restrict__ cap,
    _Float16* __restrict__ img_h, _Float16* __restrict__ cap_h,
    _Float16* __restrict__ G_h, float* __restrict__ n1) {
  __shared__ __align__(16) _Float16 capT[4 * 48 * 128];  // 48 KB
  int t = threadIdx.x;
  int lane = t & 63, wv = t >> 6;
  int b = blockIdx.x;
  if (b < N) {
    int i = b;
    const float* src = img + (size_t)i * F * D;
    _Float16* dst = img_h + (size_t)i * F * D;
    int f = t >> 2, q = t & 3;
    const float* row = src + (size_t)f * D + q * 128;
    _Float16* drow = dst + (size_t)f * D + q * 128;
    float s = 0.f;
#pragma unroll
    for (int k = 0; k < 16; ++k) {
      float4 u = *(const float4*)(row + k * 8);
      float4 v = *(const float4*)(row + k * 8 + 4);
      s += u.x * u.x + u.y * u.y + u.z * u.z + u.w * u.w;
      s += v.x * v.x + v.y * v.y + v.z * v.z + v.w * v.w;
      f16x8 h;
      h[0] = (_Float16)u.x; h[1] = (_Float16)u.y; h[2] = (_Float16)u.z; h[3] = (_Float16)u.w;
      h[4] = (_Float16)v.x; h[5] = (_Float16)v.y; h[6] = (_Float16)v.z; h[7] = (_Float16)v.w;
      *(f16x8*)(drow + k * 8) = h;
    }
    s += __shfl_xor(s, 1);
    s += __shfl_xor(s, 2);
    if (q == 0) n1[i * F + f] = sqrtf(s);
  } else {
    int j = b - N;
    const float* src = cap + (size_t)j * W * D;
    _Float16* dst = cap_h + (size_t)j * 24576;
#pragma unroll
    for (int k = 0; k < 12; ++k) {
      int slot = t + k * 256;          // 0..3071 (48 rows * 64 slots)
      int w = slot >> 6, d = (slot & 63) * 8;
      int ch = d >> 7, din = d & 127;
      float4 u = {0.f, 0.f, 0.f, 0.f}, v = {0.f, 0.f, 0.f, 0.f};
      if (w < W) {
        u = *(const float4*)(src + (size_t)w * D + d);
        v = *(const float4*)(src + (size_t)w * D + d + 4);
      }
      f16x8 h;
      h[0] = (_Float16)u.x; h[1] = (_Float16)u.y; h[2] = (_Float16)u.z; h[3] = (_Float16)u.w;
      h[4] = (_Float16)v.x; h[5] = (_Float16)v.y; h[6] = (_Float16)v.z; h[7] = (_Float16)v.w;
      int pos = din ^ ((w & 7) << 3);
      *(f16x8*)(dst + ch * 6144 + w * 128 + pos) = h;
      *(f16x8*)(capT + ch * 6144 + w * 128 + pos) = h;
    }
    __syncthreads();
    int rlo = lane & 15, koff = (lane >> 4) * 8;
    int sw = (rlo & 7) << 3;
    _Float16* gb = G_h + (size_t)j * 3072;
    if (wv < 3) {
      f32x4 acc[3];
#pragma unroll
      for (int mt = 0; mt < 3; ++mt) acc[mt] = (f32x4)0.f;
      int cb = wv * 16 + rlo;
#pragma unroll
      for (int ks = 0; ks < 16; ++ks) {
        int kk = ks * 32 + koff;
        int ch = kk >> 7, din = kk & 127;
        f16x8 bf = *(const f16x8*)(capT + ch * 6144 + cb * 128 + (din ^ sw));
#pragma unroll
        for (int mt = 0; mt < 3; ++mt) {
          int wr = mt * 16 + rlo;
          f16x8 af = *(const f16x8*)(capT + ch * 6144 + wr * 128 + (din ^ sw));
          acc[mt] = __builtin_amdgcn_mfma_f32_16x16x32_f16(af, bf, acc[mt], 0, 0, 0);
        }
      }
#pragma unroll
      for (int mt = 0; mt < 3; ++mt) {
#pragma unroll
        for (int r = 0; r < 4; ++r) {
          int w = mt * 16 + (lane >> 4) * 4 + r;
          int k = wv * 16 + rlo;
          float val = (w < W && k < W) ? acc[mt][r] : 0.f;
          gb[w * 64 + (k ^ ((w & 7) << 3))] = (_Float16)val;
        }
      }
    } else {
      for (int e = lane; e < 48 * 16; e += 64) {
        int w = e >> 4, k = 48 + (e & 15);
        gb[w * 64 + (k ^ ((w & 7) << 3))] = (_Float16)0.f;
      }
    }
  }
}

// ---------------- k_main: block = (j, 8 images), grid (8, 64) ----------------
__global__ __launch_bounds__(256, 2) void k_main(
    const _Float16* __restrict__ img_h, const _Float16* __restrict__ cap_h,
    const int* __restrict__ imgL, const int* __restrict__ capL,
    const float* __restrict__ n1g, const _Float16* __restrict__ G_h,
    float* __restrict__ Spart) {
  __shared__ __align__(16) char capB[48 * 1024];     // 48 KB: [ch][48][128] swizzled
  __shared__ __align__(16) _Float16 Gs[48 * 64];     // 6 KB
  __shared__ __align__(16) _Float16 Es[64 * 64];     // 8 KB
  __shared__ __align__(16) float rnP[40][4];         // 640 B
  __shared__ float numu[64];

  const _Float16* capS = (const _Float16*)capB;
  int t = threadIdx.x;
  int lane = t & 63, wv = t >> 6;
  int rlo = lane & 15, hi = lane >> 4;
  int koff = hi * 8, sw = (rlo & 7) << 3;
  int ig = blockIdx.x, j = blockIdx.y;
  int cL = capL[j];
  int fr = wv * 16 + rlo;

  // stage cap (48 KB) + Gram (6 KB)
  {
    const char* cb = (const char*)(cap_h + (size_t)j * 24576);
    for (int n = wv; n < 48; n += 4) gll16(cb + n * 1024 + lane * 16, capB + n * 1024);
    const char* gp = (const char*)(G_h + (size_t)j * 3072);
    for (int n = wv; n < 6; n += 4) gll16(gp + n * 1024 + lane * 16, (char*)Gs + n * 1024);
  }
  // zero Es (cols >= 48 never written later; avoids stale-LDS NaN)
  {
    uint4 z = {0u, 0u, 0u, 0u};
    ((uint4*)Es)[t] = z;
    ((uint4*)Es)[t + 256] = z;
  }
  // preload first image's B-fragments
  f16x8 cur[16];
  {
    const _Float16* ib = img_h + (size_t)(ig * 8) * 32768 + (size_t)fr * 512 + koff;
#pragma unroll
    for (int m = 0; m < 16; ++m) cur[m] = *(const f16x8*)(ib + m * 32);
  }
  __syncthreads();

#pragma unroll
  for (int ii = 0; ii < 8; ++ii) {
    const int i = ig * 8 + ii;
    const int iLv = imgL[i];

    // ---- A[w][f] = cap_w . img_f : 48 MFMA ----
    f32x4 acc[3];
#pragma unroll
    for (int mt = 0; mt < 3; ++mt) acc[mt] = (f32x4)0.f;
#pragma unroll
    for (int ch = 0; ch < 4; ++ch) {
#pragma unroll
      for (int q = 0; q < 4; ++q) {
        int col = (q * 32 + koff) ^ sw;
        f16x8 bf = cur[ch * 4 + q];
#pragma unroll
        for (int mt = 0; mt < 3; ++mt) {
          int wr = mt * 16 + rlo;
          f16x8 af = *(const f16x8*)(capS + ch * 6144 + wr * 128 + col);
          acc[mt] = __builtin_amdgcn_mfma_f32_16x16x32_f16(af, bf, acc[mt], 0, 0, 0);
        }
      }
    }
    // prefetch next image's fragments (hidden under epilogue)
    f16x8 nxt[16];
    if (ii < 7) {
      const _Float16* ib = img_h + (size_t)(i + 1) * 32768 + (size_t)fr * 512 + koff;
#pragma unroll
      for (int m = 0; m < 16; ++m) nxt[m] = *(const f16x8*)(ib + m * 32);
    }

    // ---- rnorm partials: sum_f leaky(A)^2 (f-masked), reduce over lo ----
    bool fval = (fr < iLv);
    float lk[3][4], rp[3][4];
#pragma unroll
    for (int mt = 0; mt < 3; ++mt) {
#pragma unroll
      for (int r = 0; r < 4; ++r) {
        float a = acc[mt][r];
        float l = a > 0.f ? a : 0.1f * a;
        lk[mt][r] = l;
        rp[mt][r] = fval ? l * l : 0.f;
      }
    }
#pragma unroll
    for (int s = 1; s < 16; s <<= 1) {
#pragma unroll
      for (int mt = 0; mt < 3; ++mt)
#pragma unroll
        for (int r = 0; r < 4; ++r) rp[mt][r] += __shfl_xor(rp[mt][r], s);
    }
    if (rlo == 0) {
#pragma unroll
      for (int mt = 0; mt < 3; ++mt)
#pragma unroll
        for (int r = 0; r < 4; ++r) {
          int w = mt * 16 + hi * 4 + r;
          if (w < W) rnP[w][wv] = rp[mt][r];
        }
    }
    __syncthreads();  // BAR_A: rnP visible; prev-pair Es/numu readers done

    // ---- softmax in registers: per-f max/sum over w via shfl(16,32) ----
    float lgk[3][4];
    float m = -3e38f;
#pragma unroll
    for (int mt = 0; mt < 3; ++mt) {
#pragma unroll
      for (int r = 0; r < 4; ++r) {
        int w = mt * 16 + hi * 4 + r;
        float lg = -3e38f;
        if (w < cL) {
          float4 rv = *(const float4*)&rnP[w][0];
          float rinv = rsqrtf(rv.x + rv.y + rv.z + rv.w);
          lg = LSM * lk[mt][r] * rinv;
        }
        lgk[mt][r] = lg;
        m = fmaxf(m, lg);
      }
    }
    m = fmaxf(m, __shfl_xor(m, 16));
    m = fmaxf(m, __shfl_xor(m, 32));
    float sn = 0.f;
    f16x4 ev[3];
#pragma unroll
    for (int mt = 0; mt < 3; ++mt) {
#pragma unroll
      for (int r = 0; r < 4; ++r) {
        int w = mt * 16 + hi * 4 + r;
        float e = (w < cL) ? __expf(lgk[mt][r] - m) : 0.f;
        sn = fmaf(e, acc[mt][r], sn);
        ev[mt][r] = (_Float16)e;
      }
    }
    sn += __shfl_xor(sn, 16);
    sn += __shfl_xor(sn, 32);
    if (hi == 0) numu[fr] = sn;
#pragma unroll
    for (int mt = 0; mt < 3; ++mt)
      *(f16x4*)&Es[fr * 64 + ((mt * 16 + hi * 4) ^ sw)] = ev[mt];
    __syncthreads();  // BAR_B: Es + numu visible

    // ---- P = E*G (6 MFMA); n2^2 = sum P.E; sim; LSE partial ----
    f32x4 P[3];
#pragma unroll
    for (int nt = 0; nt < 3; ++nt) P[nt] = (f32x4)0.f;
#pragma unroll
    for (int k0 = 0; k0 < 64; k0 += 32) {
      int kk = k0 + koff;
      f16x8 ea = *(const f16x8*)&Es[fr * 64 + (kk ^ sw)];
#pragma unroll
      for (int nt = 0; nt < 3; ++nt) {
        int wr = nt * 16 + rlo;
        f16x8 gbf = *(const f16x8*)&Gs[wr * 64 + (kk ^ sw)];
        P[nt] = __builtin_amdgcn_mfma_f32_16x16x32_f16(ea, gbf, P[nt], 0, 0, 0);
      }
    }
    float n2p[4] = {0.f, 0.f, 0.f, 0.f};
#pragma unroll
    for (int nt = 0; nt < 3; ++nt) {
      int wcol = nt * 16 + rlo;
#pragma unroll
      for (int r = 0; r < 4; ++r) {
        int fr2 = wv * 16 + hi * 4 + r;
        float evv = (float)Es[fr2 * 64 + (wcol ^ ((fr2 & 7) << 3))];
        n2p[r] = fmaf(P[nt][r], evv, n2p[r]);
      }
    }
#pragma unroll
    for (int d2 = 1; d2 < 16; d2 <<= 1) {
#pragma unroll
      for (int r = 0; r < 4; ++r) n2p[r] += __shfl_xor(n2p[r], d2);
    }
    int r = lane & 3;
    float n2sq = n2p[0];
    if (r == 1) n2sq = n2p[1];
    if (r == 2) n2sq = n2p[2];
    if (r == 3) n2sq = n2p[3];
    int fmy = wv * 16 + hi * 4 + r;
    float nm = numu[fmy];
    float n1v = n1g[i * F + fmy];
    float denom = n1v * sqrtf(fmaxf(n2sq, 0.f));
    float sim = nm / fmaxf(denom, 1e-20f);
    float ef = (fmy < iLv) ? __expf(LLSE * sim) : 0.f;
    float val = ((lane & 12) == 0) ? ef : 0.f;
#pragma unroll
    for (int d2 = 1; d2 < 64; d2 <<= 1) val += __shfl_xor(val, d2);
    if (lane == 0) Spart[((j << 6) + i) * 4 + wv] = val;

    // rotate prefetch
    if (ii < 7) {
#pragma unroll
      for (int m2 = 0; m2 < 16; ++m2) cur[m2] = nxt[m2];
    }
  }
}

// ---------------- k_loss: combine partials + contrastive reduction ----------------
__global__ __launch_bounds__(256) void k_loss(const float* __restrict__ Spart,
                                              float* __restrict__ out) {
  __shared__ float Sl[4096];
  __shared__ float red[128];
  int t = threadIdx.x;
  for (int idx = t; idx < 4096; idx += 256) {
    float4 p = *(const float4*)(Spart + (idx << 2));
    Sl[idx] = __logf(p.x + p.y + p.z + p.w) * (1.f / LLSE);
  }
  __syncthreads();
  if (t < 128) {
    float m = -1e30f;
    if (t < 64) {
      int a = t;
      float da = Sl[a * 64 + a];
      for (int b = 0; b < 64; ++b)
        if (b != a) m = fmaxf(m, MARG + Sl[a * 64 + b] - da);
    } else {
      int b = t - 64;
      float db = Sl[b * 64 + b];
      for (int a = 0; a < 64; ++a)
        if (a != b) m = fmaxf(m, MARG + Sl[a * 64 + b] - db);
    }
    red[t] = fmaxf(m, 0.f);
  }
  __syncthreads();
  if (t == 0) {
    float s = 0.f;
    for (int k = 0; k < 128; ++k) s += red[k];
    *out = s;
  }
}

extern "C" void kernel_launch(void* const* d_in, const int* in_sizes, int n_in,
                              void* d_out, int out_size, void* d_ws, size_t ws_size,
                              hipStream_t stream) {
  const float* img = (const float*)d_in[0];
  const float* cap = (const float*)d_in[1];
  const int* imgL = (const int*)d_in[2];
  const int* capL = (const int*)d_in[3];

  char* wsb = (char*)d_ws;
  float* n1 = (float*)wsb;                                // 16 KB
  float* Spart = (float*)(wsb + 16384);                   // 64 KB
  _Float16* img_h = (_Float16*)(wsb + 81920);             // 4 MB
  _Float16* cap_h = (_Float16*)(wsb + 81920 + 4194304);   // 3 MB
  _Float16* G_h = (_Float16*)(wsb + 81920 + 4194304 + 3145728);  // 384 KB

  k_pre<<<128, 256, 0, stream>>>(img, cap, img_h, cap_h, G_h, n1);
  dim3 grid(8, 64);
  k_main<<<grid, 256, 0, stream>>>(img_h, cap_h, imgL, capL, n1, G_h, Spart);
  k_loss<<<1, 256, 0, stream>>>(Spart, (float*)d_out);
}

// Round 5
// 82.838 us; speedup vs baseline: 1.0370x; 1.0370x over previous
//
#include <hip/hip_runtime.h>
#include <math.h>

#define N 64
#define F 64
#define W 40
#define D 512
#define LSM 9.0f
#define LLSE 6.0f
#define MARG 0.2f

typedef _Float16 f16x8 __attribute__((ext_vector_type(8)));
typedef _Float16 f16x4 __attribute__((ext_vector_type(4)));
typedef float f32x4 __attribute__((ext_vector_type(4)));

__device__ inline void gll16(const void* g, void* l) {
  __builtin_amdgcn_global_load_lds(
      (const __attribute__((address_space(1))) unsigned int*)g,
      (__attribute__((address_space(3))) unsigned int*)l, 16, 0, 0);
}

// layouts (halves):
//  img_h per i: 64*512 linear [f][d]                                  (32768)
//  cap_h per j: [ch][w48][128], half-idx ^ ((w&7)<<3), rows 40..47=0  (24576)
//  G_h  per j: [w48][64], ^ ((w&7)<<3), zero outside 40x40            (3072)

// ---------------- k_pre ----------------
__global__ __launch_bounds__(256) void k_pre(
    const float* __restrict__ img, const float* __restrict__ cap,
    _Float16* __restrict__ img_h, _Float16* __restrict__ cap_h,
    _Float16* __restrict__ G_h, float* __restrict__ n1) {
  __shared__ __align__(16) _Float16 capT[4 * 48 * 128];  // 48 KB
  int t = threadIdx.x;
  int lane = t & 63, wv = t >> 6;
  int b = blockIdx.x;
  if (b < N) {
    int i = b;
    const float* src = img + (size_t)i * F * D;
    _Float16* dst = img_h + (size_t)i * F * D;
    int f = t >> 2, q = t & 3;
    const float* row = src + (size_t)f * D + q * 128;
    _Float16* drow = dst + (size_t)f * D + q * 128;
    float s = 0.f;
#pragma unroll
    for (int k = 0; k < 16; ++k) {
      float4 u = *(const float4*)(row + k * 8);
      float4 v = *(const float4*)(row + k * 8 + 4);
      s += u.x * u.x + u.y * u.y + u.z * u.z + u.w * u.w;
      s += v.x * v.x + v.y * v.y + v.z * v.z + v.w * v.w;
      f16x8 h;
      h[0] = (_Float16)u.x; h[1] = (_Float16)u.y; h[2] = (_Float16)u.z; h[3] = (_Float16)u.w;
      h[4] = (_Float16)v.x; h[5] = (_Float16)v.y; h[6] = (_Float16)v.z; h[7] = (_Float16)v.w;
      *(f16x8*)(drow + k * 8) = h;
    }
    s += __shfl_xor(s, 1);
    s += __shfl_xor(s, 2);
    if (q == 0) n1[i * F + f] = sqrtf(s);
  } else {
    int j = b - N;
    const float* src = cap + (size_t)j * W * D;
    _Float16* dst = cap_h + (size_t)j * 24576;
#pragma unroll
    for (int k = 0; k < 12; ++k) {
      int slot = t + k * 256;          // 48 rows * 64 slots
      int w = slot >> 6, d = (slot & 63) * 8;
      int ch = d >> 7, din = d & 127;
      float4 u = {0.f, 0.f, 0.f, 0.f}, v = {0.f, 0.f, 0.f, 0.f};
      if (w < W) {
        u = *(const float4*)(src + (size_t)w * D + d);
        v = *(const float4*)(src + (size_t)w * D + d + 4);
      }
      f16x8 h;
      h[0] = (_Float16)u.x; h[1] = (_Float16)u.y; h[2] = (_Float16)u.z; h[3] = (_Float16)u.w;
      h[4] = (_Float16)v.x; h[5] = (_Float16)v.y; h[6] = (_Float16)v.z; h[7] = (_Float16)v.w;
      int pos = din ^ ((w & 7) << 3);
      *(f16x8*)(dst + ch * 6144 + w * 128 + pos) = h;
      *(f16x8*)(capT + ch * 6144 + w * 128 + pos) = h;
    }
    __syncthreads();
    int rlo = lane & 15, koff = (lane >> 4) * 8;
    int sw = (rlo & 7) << 3;
    _Float16* gb = G_h + (size_t)j * 3072;
    if (wv < 3) {
      f32x4 acc[3];
#pragma unroll
      for (int mt = 0; mt < 3; ++mt) acc[mt] = (f32x4)0.f;
      int cb = wv * 16 + rlo;
#pragma unroll
      for (int ks = 0; ks < 16; ++ks) {
        int kk = ks * 32 + koff;
        int ch = kk >> 7, din = kk & 127;
        f16x8 bf = *(const f16x8*)(capT + ch * 6144 + cb * 128 + (din ^ sw));
#pragma unroll
        for (int mt = 0; mt < 3; ++mt) {
          int wr = mt * 16 + rlo;
          f16x8 af = *(const f16x8*)(capT + ch * 6144 + wr * 128 + (din ^ sw));
          acc[mt] = __builtin_amdgcn_mfma_f32_16x16x32_f16(af, bf, acc[mt], 0, 0, 0);
        }
      }
#pragma unroll
      for (int mt = 0; mt < 3; ++mt) {
#pragma unroll
        for (int r = 0; r < 4; ++r) {
          int w = mt * 16 + (lane >> 4) * 4 + r;
          int k = wv * 16 + rlo;
          float val = (w < W && k < W) ? acc[mt][r] : 0.f;
          gb[w * 64 + (k ^ ((w & 7) << 3))] = (_Float16)val;
        }
      }
    } else {
      for (int e = lane; e < 48 * 16; e += 64) {
        int w = e >> 4, k = 48 + (e & 15);
        gb[w * 64 + (k ^ ((w & 7) << 3))] = (_Float16)0.f;
      }
    }
  }
}

// ---------------- k_main: ONE WAVE = ONE (i,j) PAIR; block = 4 waves, same j ----
// grid 1024: bid -> xcd = bid&7 (i-octet pinned per XCD), s = bid>>3,
//            ig = xcd*2 + (s&1) (4-image group), j = s>>1, i = ig*4 + wv.
// Zero barriers after staging: all reductions via shfl; Es is per-wave private.
__global__ __launch_bounds__(256, 2) void k_main(
    const _Float16* __restrict__ img_h, const _Float16* __restrict__ cap_h,
    const int* __restrict__ imgL, const int* __restrict__ capL,
    const float* __restrict__ n1g, const _Float16* __restrict__ G_h,
    float* __restrict__ S) {
  __shared__ __align__(16) _Float16 capS[4 * 48 * 128];  // 49152 B, swizzled
  __shared__ __align__(16) _Float16 Gs[48 * 64];         // 6144 B, swizzled
  __shared__ __align__(16) _Float16 Es[4][3136];         // 4 x 6272 B (64x48 + 64 pad)

  int t = threadIdx.x;
  int lane = t & 63, wv = t >> 6;
  int rlo = lane & 15, hi = lane >> 4;
  int koff = hi * 8;
  int sw = (rlo & 7) << 3;

  int bid = blockIdx.x;
  int xcd = bid & 7, s0 = bid >> 3;
  int ig = xcd * 2 + (s0 & 1);
  int j = s0 >> 1;
  int i = ig * 4 + wv;

  int iL = imgL[i], cL = capL[j];
  _Float16* Ew = &Es[wv][0];

  // stage cap (48 KB) + Gram (6 KB)
  {
    const char* cb = (const char*)(cap_h + (size_t)j * 24576);
    for (int n = wv; n < 48; n += 4) gll16(cb + n * 1024 + lane * 16, (char*)capS + n * 1024);
    const char* gp = (const char*)(G_h + (size_t)j * 3072);
    for (int n = wv; n < 6; n += 4) gll16(gp + n * 1024 + lane * 16, (char*)Gs + n * 1024);
  }
  // zero the 64-half Es pad (row-63 K-spill target); rest is fully overwritten
  if (lane < 8) *(f16x8*)(Ew + 3072 + lane * 8) = (f16x8)(_Float16)0.f;

  float n1lane = n1g[i * 64 + lane];

  // img B-fragments: rows f = nt*16+rlo, prefetch ping-pong, issued pre-barrier
  const _Float16* ibase = img_h + (size_t)i * 32768 + (size_t)rlo * 512 + koff;
  f16x8 bf0[4], bf1[4];
#pragma unroll
  for (int nt = 0; nt < 4; ++nt) bf0[nt] = *(const f16x8*)(ibase + nt * 8192);

  f32x4 acc[3][4];
#pragma unroll
  for (int mt = 0; mt < 3; ++mt)
#pragma unroll
    for (int nt = 0; nt < 4; ++nt) acc[mt][nt] = (f32x4)0.f;

  __syncthreads();  // the ONLY barrier

  // ---- A-phase: A[w][f] = cap_w . img_f  (192 MFMA, 48 af reads, 4x reuse) ----
#pragma unroll
  for (int ks = 0; ks < 16; ++ks) {
    if (ks < 15) {
#pragma unroll
      for (int nt = 0; nt < 4; ++nt) {
        f16x8 v = *(const f16x8*)(ibase + nt * 8192 + (ks + 1) * 32);
        if (ks & 1) bf0[nt] = v; else bf1[nt] = v;
      }
    }
    int kk = ks * 32 + koff;
    int ch = kk >> 7, din = kk & 127;
    const _Float16* cbase = capS + ch * 6144 + (din ^ sw);
#pragma unroll
    for (int mt = 0; mt < 3; ++mt) {
      f16x8 af = *(const f16x8*)(cbase + (mt * 16 + rlo) * 128);
#pragma unroll
      for (int nt = 0; nt < 4; ++nt) {
        f16x8 b = (ks & 1) ? bf1[nt] : bf0[nt];
        acc[mt][nt] = __builtin_amdgcn_mfma_f32_16x16x32_f16(af, b, acc[mt][nt], 0, 0, 0);
      }
    }
  }

  // ---- rnorm: sum over f of leaky(A)^2 (f-masked): regs over nt + shfl over rlo ----
  float rinv[3][4];
#pragma unroll
  for (int mt = 0; mt < 3; ++mt)
#pragma unroll
    for (int r = 0; r < 4; ++r) {
      float s = 0.f;
#pragma unroll
      for (int nt = 0; nt < 4; ++nt) {
        float a = acc[mt][nt][r];
        float l = a > 0.f ? a : 0.1f * a;
        s += ((nt * 16 + rlo) < iL) ? l * l : 0.f;
      }
#pragma unroll
      for (int d = 1; d < 16; d <<= 1) s += __shfl_xor(s, d);
      rinv[mt][r] = 1.f / (sqrtf(s) + 1e-8f);
    }

  // ---- logits + per-f max over w (regs over mt,r + shfl 16,32) ----
  float lgk[3][4][4];
  float mx[4] = {-3e38f, -3e38f, -3e38f, -3e38f};
#pragma unroll
  for (int mt = 0; mt < 3; ++mt)
#pragma unroll
    for (int nt = 0; nt < 4; ++nt)
#pragma unroll
      for (int r = 0; r < 4; ++r) {
        int w = mt * 16 + hi * 4 + r;
        float a = acc[mt][nt][r];
        float l = a > 0.f ? a : 0.1f * a;
        float lg = (w < cL) ? LSM * l * rinv[mt][r] : -3e38f;
        lgk[mt][nt][r] = lg;
        mx[nt] = fmaxf(mx[nt], lg);
      }
#pragma unroll
  for (int nt = 0; nt < 4; ++nt) {
    mx[nt] = fmaxf(mx[nt], __shfl_xor(mx[nt], 16));
    mx[nt] = fmaxf(mx[nt], __shfl_xor(mx[nt], 32));
  }

  // ---- e = exp(lg - m); sn = sum e*A; write E (64x48 fp16, per-wave) ----
  float sn[4] = {0.f, 0.f, 0.f, 0.f};
#pragma unroll
  for (int mt = 0; mt < 3; ++mt)
#pragma unroll
    for (int nt = 0; nt < 4; ++nt) {
      f16x4 ev;
#pragma unroll
      for (int r = 0; r < 4; ++r) {
        int w = mt * 16 + hi * 4 + r;
        float e = (w < cL) ? __expf(lgk[mt][nt][r] - mx[nt]) : 0.f;
        sn[nt] = fmaf(e, acc[mt][nt][r], sn[nt]);
        ev[r] = (_Float16)e;
      }
      *(f16x4*)(Ew + (nt * 16 + rlo) * 48 + mt * 16 + hi * 4) = ev;
    }
#pragma unroll
  for (int nt = 0; nt < 4; ++nt) {
    sn[nt] += __shfl_xor(sn[nt], 16);
    sn[nt] += __shfl_xor(sn[nt], 32);
  }

  // ---- P = E*G (24 MFMA, K=48: Gs cols 40..63 are stored zeros) ----
  f32x4 P[4][3];
#pragma unroll
  for (int mtl = 0; mtl < 4; ++mtl)
#pragma unroll
    for (int ntl = 0; ntl < 3; ++ntl) P[mtl][ntl] = (f32x4)0.f;
#pragma unroll
  for (int ks2 = 0; ks2 < 2; ++ks2) {
    int kk2 = ks2 * 32 + koff;
    f16x8 bfg[3];
#pragma unroll
    for (int ntl = 0; ntl < 3; ++ntl)
      bfg[ntl] = *(const f16x8*)(Gs + (ntl * 16 + rlo) * 64 + (kk2 ^ sw));
#pragma unroll
    for (int mtl = 0; mtl < 4; ++mtl) {
      f16x8 af = *(const f16x8*)(Ew + (mtl * 16 + rlo) * 48 + kk2);
#pragma unroll
      for (int ntl = 0; ntl < 3; ++ntl)
        P[mtl][ntl] = __builtin_amdgcn_mfma_f32_16x16x32_f16(af, bfg[ntl], P[mtl][ntl], 0, 0, 0);
    }
  }

  // ---- n2^2 = sum_w P.E per f; sim; LSE over f; one store per wave ----
  float ef = 0.f;
#pragma unroll
  for (int mtl = 0; mtl < 4; ++mtl) {
#pragma unroll
    for (int rr = 0; rr < 4; ++rr) {
      float n2s = 0.f;
#pragma unroll
      for (int ntl = 0; ntl < 3; ++ntl) {
        float evv = (float)Ew[(mtl * 16 + hi * 4 + rr) * 48 + ntl * 16 + rlo];
        n2s = fmaf(P[mtl][ntl][rr], evv, n2s);
      }
#pragma unroll
      for (int d = 1; d < 16; d <<= 1) n2s += __shfl_xor(n2s, d);
      int fm = mtl * 16 + hi * 4 + rr;
      float nm = __shfl(sn[mtl], hi * 4 + rr);
      float n1v = __shfl(n1lane, fm);
      float denom = n1v * sqrtf(fmaxf(n2s, 0.f));
      float sim = nm / fmaxf(denom, 1e-20f);
      ef += (fm < iL) ? __expf(LLSE * sim) : 0.f;
    }
  }
  ef += __shfl_xor(ef, 16);
  ef += __shfl_xor(ef, 32);
  if (lane == 0) S[(j << 6) + i] = __logf(ef) * (1.f / LLSE);
}

// ---------------- k_loss ----------------
__global__ void k_loss(const float* __restrict__ S, float* __restrict__ out) {
  __shared__ float red[128];
  int t = threadIdx.x;
  float m = -1e30f;
  if (t < 64) {
    int a = t;
    float da = S[a * N + a];
    for (int b = 0; b < N; ++b)
      if (b != a) m = fmaxf(m, MARG + S[a * N + b] - da);
  } else {
    int b = t - 64;
    float db = S[b * N + b];
    for (int a = 0; a < N; ++a)
      if (a != b) m = fmaxf(m, MARG + S[a * N + b] - db);
  }
  m = fmaxf(m, 0.f);
  red[t] = m;
  __syncthreads();
  if (t == 0) {
    float s = 0.f;
    for (int k = 0; k < 128; ++k) s += red[k];
    *out = s;
  }
}

extern "C" void kernel_launch(void* const* d_in, const int* in_sizes, int n_in,
                              void* d_out, int out_size, void* d_ws, size_t ws_size,
                              hipStream_t stream) {
  const float* img = (const float*)d_in[0];
  const float* cap = (const float*)d_in[1];
  const int* imgL = (const int*)d_in[2];
  const int* capL = (const int*)d_in[3];

  char* wsb = (char*)d_ws;
  float* n1 = (float*)wsb;                                // 16 KB
  float* S = (float*)(wsb + 16384);                       // 16 KB
  _Float16* img_h = (_Float16*)(wsb + 32768);             // 4 MB
  _Float16* cap_h = (_Float16*)(wsb + 32768 + 4194304);   // 3 MB
  _Float16* G_h = (_Float16*)(wsb + 32768 + 4194304 + 3145728);  // 384 KB

  k_pre<<<128, 256, 0, stream>>>(img, cap, img_h, cap_h, G_h, n1);
  k_main<<<1024, 256, 0, stream>>>(img_h, cap_h, imgL, capL, n1, G_h, S);
  k_loss<<<1, 128, 0, stream>>>(S, (float*)d_out);
}